// Round 12
// baseline (194.917 us; speedup 1.0000x reference)
//
#include <hip/hip_runtime.h>
#include <math.h>

// R21: SPLIT-K flash. Evidence R15/R20: flash time == longest chunk's
// serialized chain (33 iters x ~3800cy = 52us; balance/LDS/occupancy all
// no-ops because makespan = longest block). Fix: halve the chain. 512-thr
// blocks; waves 0-3 = k-tiles [0,h), waves 4-7 = [h,c+1) for the SAME 64
// q-rows; each group runs the R20-verified loop body on its own K/V dbuf
// ([grp]-indexed LDS, 64KB -> 2 blk/CU, 16 waves/CU unchanged). Uniform
// barrier count (loop bound = group1 count; work guarded i<cg). Final
// in-LDS combine: O = O0*2^(m0-m) + O1*2^(m1-m), l likewise; group0
// stores. Empty group0 (c=0): m=-inf -> weight 0 (exp2(-inf)=0, no NaN).
// qkv/out: R17 exact (best-known GEMM config; prefetch family dead x3).
// Layouts (verified R2-R20, absmax 7.8e-3):
//   x32 A-frag: m=lane&15, k=(lane>>4)*8+j ; B-frag: n=lane&15, k=(lane>>4)*8+j
//   x16 A/B-frag: idx=lane&15, k=(lane>>4)*4+j
//   C/D (all 16x16): col=lane&15, row=(lane>>4)*4+reg

#define SS_ 2048
#define DD_ 1024
#define NH_ 16
#define BN_ 32
#define BS_ 4096

typedef __bf16 bf16x8 __attribute__((ext_vector_type(8)));
typedef __bf16 bf16x4 __attribute__((ext_vector_type(4)));
typedef short shortx4 __attribute__((ext_vector_type(4)));
typedef float floatx4 __attribute__((ext_vector_type(4)));
typedef unsigned short ushortx4 __attribute__((ext_vector_type(4)));

__device__ __forceinline__ unsigned short f2bf(float f) {
    union { float f; unsigned u; } v; v.f = f;
    unsigned r = v.u + 0x7FFFu + ((v.u >> 16) & 1u);   // RNE
    return (unsigned short)(r >> 16);
}

__device__ __forceinline__ floatx4 mfma_pv(bf16x4 a, bf16x4 b, floatx4 c) {
#if __has_builtin(__builtin_amdgcn_mfma_f32_16x16x16_bf16)
    return __builtin_amdgcn_mfma_f32_16x16x16_bf16(a, b, c, 0, 0, 0);
#else
    return __builtin_amdgcn_mfma_f32_16x16x16bf16_1k(
        __builtin_bit_cast(shortx4, a), __builtin_bit_cast(shortx4, b), c, 0, 0, 0);
#endif
}

__device__ __forceinline__ void gl_lds16(const unsigned short* g, unsigned short* l) {
    __builtin_amdgcn_global_load_lds(
        (const __attribute__((address_space(1))) unsigned int*)g,
        (__attribute__((address_space(3))) unsigned int*)l, 16, 0, 0);
}

// ---------- K0a: cast resid + WQ/WK/WV to bf16 (1D grid) ----------
__global__ __launch_bounds__(256) void cast_bf16_kernel(
    const float* __restrict__ resid, const float* __restrict__ WQ,
    const float* __restrict__ WK, const float* __restrict__ WV,
    unsigned short* __restrict__ residB, unsigned short* __restrict__ WQb,
    unsigned short* __restrict__ WKb, unsigned short* __restrict__ WVb)
{
    const int x = blockIdx.x;
    int z, ix;
    if (x < 4096) { z = 0; ix = x; }
    else { z = 1 + ((x - 4096) >> 10); ix = (x - 4096) & 1023; }
    const float* src = (z == 0) ? resid : (z == 1) ? WQ : (z == 2) ? WK : WV;
    unsigned short* dst = (z == 0) ? residB : (z == 1) ? WQb : (z == 2) ? WKb : WVb;
    const int i = (ix * 256 + threadIdx.x) * 4;
    float4 f = *(const float4*)(src + i);
    ushortx4 o;
    o[0] = f2bf(f.x); o[1] = f2bf(f.y); o[2] = f2bf(f.z); o[3] = f2bf(f.w);
    *(ushortx4*)(dst + i) = o;
}

// ---------- K0b: WO [kk=n*64+h][d] fp32 -> WOt [d][kk] bf16 ----------
__global__ __launch_bounds__(256) void wo_transpose_kernel(
    const float* __restrict__ WO, unsigned short* __restrict__ WOt)
{
    __shared__ float t[64][65];
    const int kk0 = blockIdx.x * 64, d0 = blockIdx.y * 64;
    #pragma unroll
    for (int it = 0; it < 16; ++it) {
        int idx = it * 256 + threadIdx.x;
        int r = idx >> 6, c = idx & 63;
        t[r][c] = WO[(kk0 + r) * DD_ + d0 + c];
    }
    __syncthreads();
    #pragma unroll
    for (int it = 0; it < 16; ++it) {
        int idx = it * 256 + threadIdx.x;
        int r = idx >> 6, c = idx & 63;
        WOt[(d0 + r) * DD_ + kk0 + c] = f2bf(t[c][r]);
    }
}

// ---------- K1: FUSED QKV GEMM (R17 exact: BM=128, BN=64, 512 thr) ----------
__global__ __launch_bounds__(512, 4) void qkv_fused_kernel(
    const unsigned short* __restrict__ residB,
    const unsigned short* __restrict__ WQb,
    const unsigned short* __restrict__ WKb,
    const unsigned short* __restrict__ WVb,
    unsigned short* __restrict__ q, unsigned short* __restrict__ kk,
    unsigned short* __restrict__ vT)
{
    __shared__ unsigned short As[128 * 64];
    __shared__ unsigned short Bq[64 * 64];
    __shared__ unsigned short Bk[64 * 64];
    __shared__ unsigned short Bv[64 * 64];
    const int tid = threadIdx.x;
    const int l = tid & 63, w = tid >> 6;          // w: 0..7
    const int quad = l >> 4, lan = l & 15;
    const int mBase = blockIdx.x * 128;
    const int head = blockIdx.y;                   // BN=64 == one head
    const int nBase = head * 64;

    floatx4 accQ[4], accK[4], accV[4];
    #pragma unroll
    for (int ni = 0; ni < 4; ++ni)
        #pragma unroll
        for (int i = 0; i < 4; ++i) {
            accQ[ni][i] = 0.f; accK[ni][i] = 0.f; accV[ni][i] = 0.f;
        }

    const int sr = l >> 3;
    const int sgx = ((l & 7) ^ sr) * 8;

    for (int k0 = 0; k0 < DD_; k0 += 64) {
        __syncthreads();
        gl_lds16(residB + (size_t)(mBase + w * 16 + sr) * DD_ + k0 + sgx,
                 As + (w * 16) * 64);
        gl_lds16(residB + (size_t)(mBase + w * 16 + 8 + sr) * DD_ + k0 + sgx,
                 As + (w * 16 + 8) * 64);
        gl_lds16(WQb + (size_t)(nBase + w * 8 + sr) * DD_ + k0 + sgx,
                 Bq + (w * 8) * 64);
        gl_lds16(WKb + (size_t)(nBase + w * 8 + sr) * DD_ + k0 + sgx,
                 Bk + (w * 8) * 64);
        gl_lds16(WVb + (size_t)(nBase + w * 8 + sr) * DD_ + k0 + sgx,
                 Bv + (w * 8) * 64);
        __syncthreads();
        #pragma unroll
        for (int ks = 0; ks < 2; ++ks) {
            const int fo = (((ks * 4 + quad) ^ (lan & 7)) << 3);
            bf16x8 a = *(const bf16x8*)(As + (w * 16 + lan) * 64 + fo);
            bf16x8 bq[4], bk[4], bv[4];
            #pragma unroll
            for (int ni = 0; ni < 4; ++ni) {
                bq[ni] = *(const bf16x8*)(Bq + (ni * 16 + lan) * 64 + fo);
                bk[ni] = *(const bf16x8*)(Bk + (ni * 16 + lan) * 64 + fo);
                bv[ni] = *(const bf16x8*)(Bv + (ni * 16 + lan) * 64 + fo);
            }
            #pragma unroll
            for (int ni = 0; ni < 4; ++ni) {
                accQ[ni] = __builtin_amdgcn_mfma_f32_16x16x32_bf16(a, bq[ni], accQ[ni], 0, 0, 0);
                accK[ni] = __builtin_amdgcn_mfma_f32_16x16x32_bf16(a, bk[ni], accK[ni], 0, 0, 0);
                accV[ni] = __builtin_amdgcn_mfma_f32_16x16x32_bf16(a, bv[ni], accV[ni], 0, 0, 0);
            }
        }
    }
    const int m0 = mBase + w * 16 + quad * 4;
    const int bb = m0 >> 11, ss0 = m0 & 2047;
    const float scl = 0.125f * 1.44269504088896340736f;
    #pragma unroll
    for (int ni = 0; ni < 4; ++ni) {
        const int h = ni * 16 + lan;
        bf16x4 obq, obv;
        #pragma unroll
        for (int reg = 0; reg < 4; ++reg) {
            obq[reg] = static_cast<__bf16>(accQ[ni][reg] * scl);
            obv[reg] = static_cast<__bf16>(accV[ni][reg]);
        }
        *(bf16x4*)(q  + ((size_t)(bb * NH_ + head) * 64 + h) * SS_ + ss0) = obq;
        *(bf16x4*)(vT + ((size_t)(bb * NH_ + head) * 64 + h) * SS_ + ss0) = obv;
        #pragma unroll
        for (int reg = 0; reg < 4; ++reg)
            kk[((size_t)(bb * NH_ + head) * SS_ + ss0 + reg) * 64 + h] =
                f2bf(accK[ni][reg]);
    }
}

// ---------- K2: flash attention, SPLIT-K (2 wave-groups) ----------
__global__ __launch_bounds__(512) void flash_mfma_kernel(
    const unsigned short* __restrict__ q,
    const unsigned short* __restrict__ k,
    const unsigned short* __restrict__ vT,
    unsigned short* __restrict__ attn)
{
    // [grp][kv(0=K,1=V)][buf][64*64] = 64KB; reused as combine scratch
    __shared__ unsigned short ldsBuf[2][2][2][64 * 64];
    const int l = threadIdx.x & 63, w = threadIdx.x >> 6;   // w: 0..7
    const int grp = w >> 2;                                 // k-half
    const int wl = w & 3;                                   // wave in group
    const int quad = l >> 4, lan = l & 15;
    const int f = blockIdx.x;                               // 0..1023
    const int bn = (f & 7) | (((f >> 3) & 3) << 3);         // XCD swizzle
    const int g = f >> 5;                                   // 0..31
    const int ch = (g < 8) ? (31 - g)
                 : (g < 16) ? (g + 8)
                 : (g < 24) ? (15 - (g - 16))
                 : (g - 24);

    const unsigned short* Qg = q  + (size_t)bn * 64 * SS_;  // [h][s]
    const unsigned short* Kg = k  + (size_t)bn * SS_ * 64;  // [s][h]
    const unsigned short* Vg = vT + (size_t)bn * 64 * SS_;  // [h][s]

    const int srl = l >> 3;
    const int sgx = (l & 7) ^ srl;

    const int qAbs = ch * 64 + wl * 16 + lan;

    // split: group0 tiles [0,h), group1 tiles [h, ch+1)
    const int half = (ch + 1) >> 1;
    const int base = grp ? half : 0;
    const int cg   = grp ? (ch + 1 - half) : half;   // this group's count
    const int nIt  = ch + 1 - half;                  // uniform loop bound (>= cg)

    // Q from [h][s]: 16 strided scalar loads, once per block (cheap)
    bf16x8 Qf0, Qf1;
    #pragma unroll
    for (int j = 0; j < 8; ++j) {
        Qf0[j] = *(const __bf16*)(Qg + (size_t)(quad * 8 + j) * SS_ + qAbs);
        Qf1[j] = *(const __bf16*)(Qg + (size_t)(quad * 8 + j + 32) * SS_ + qAbs);
    }

    bf16x4 ones;
    #pragma unroll
    for (int i = 0; i < 4; ++i) ones[i] = static_cast<__bf16>(1.0f);

    float mrow = -INFINITY;
    floatx4 l_acc;
    floatx4 o[4];
    #pragma unroll
    for (int i = 0; i < 4; ++i) l_acc[i] = 0.f;
    #pragma unroll
    for (int t = 0; t < 4; ++t)
        #pragma unroll
        for (int i = 0; i < 4; ++i) o[t][i] = 0.f;

    #define STAGE_K(kt_, buf_)                                                  \
        { const int row0_ = wl * 16, kB_ = (kt_) * 64;                          \
          gl_lds16(Kg + (size_t)(kB_ + row0_ + srl) * 64 + sgx * 8,             \
                   &ldsBuf[grp][0][buf_][row0_ * 64]);                          \
          gl_lds16(Kg + (size_t)(kB_ + row0_ + 8 + srl) * 64 + sgx * 8,         \
                   &ldsBuf[grp][0][buf_][(row0_ + 8) * 64]); }
    #define STAGE_V(kt_, buf_)                                                  \
        { const int row0_ = wl * 16, kB_ = (kt_) * 64;                          \
          gl_lds16(Vg + (size_t)(row0_ + srl) * SS_ + kB_ + sgx * 8,            \
                   &ldsBuf[grp][1][buf_][row0_ * 64]);                          \
          gl_lds16(Vg + (size_t)(row0_ + 8 + srl) * SS_ + kB_ + sgx * 8,        \
                   &ldsBuf[grp][1][buf_][(row0_ + 8) * 64]); }
    #define QK_TILE(dst_, buf_)                                                 \
        { const unsigned short* Kb_ = &ldsBuf[grp][0][buf_][0];                 \
          bf16x8 K0v_[4], K1v_[4];                                              \
          _Pragma("unroll")                                                     \
          for (int nt = 0; nt < 4; ++nt) {                                      \
              const unsigned short* kr_ = Kb_ + (nt * 16 + lan) * 64;           \
              K0v_[nt] = *(const bf16x8*)(kr_ + ((quad ^ (lan & 7)) << 3));     \
              K1v_[nt] = *(const bf16x8*)(kr_ + (((quad + 4) ^ (lan & 7)) << 3)); } \
          _Pragma("unroll")                                                     \
          for (int nt = 0; nt < 4; ++nt) {                                      \
              floatx4 zz_; zz_[0] = zz_[1] = zz_[2] = zz_[3] = 0.f;             \
              dst_[nt] = __builtin_amdgcn_mfma_f32_16x16x32_bf16(K0v_[nt], Qf0, zz_, 0, 0, 0); \
              dst_[nt] = __builtin_amdgcn_mfma_f32_16x16x32_bf16(K1v_[nt], Qf1, dst_[nt], 0, 0, 0); } }

    // prologue (one barrier, all waves)
    if (cg >= 1) { STAGE_K(base, 0); STAGE_V(base, 0); }
    __syncthreads();
    if (cg >= 2) STAGE_K(base + 1, 1);
    floatx4 scCur[4], scNext[4];
    if (cg >= 1) QK_TILE(scCur, 0);

    for (int i = 0; i < nIt; ++i) {
        __syncthreads();   // uniform: all 8 waves, every iteration
        if (i < cg) {
            const int t = base + i;
            if (i + 2 < cg) STAGE_K(base + i + 2, (i + 2) & 1);
            if (i + 1 < cg) {
                STAGE_V(base + i + 1, (i + 1) & 1);
                QK_TILE(scNext, (i + 1) & 1);
            }
            // batched V reads for tile t (staged with parity i&1)
            const unsigned short* Vb = &ldsBuf[grp][1][i & 1][0];
            bf16x4 Vfv[4][4];
            #pragma unroll
            for (int tt = 0; tt < 4; ++tt) {
                const unsigned short* vr = Vb + (tt * 16 + lan) * 64 + ((quad & 1) << 2);
                #pragma unroll
                for (int nt = 0; nt < 4; ++nt) {
                    const int g2 = nt * 2 + (quad >> 1);
                    Vfv[tt][nt] = *(const bf16x4*)(vr + ((g2 ^ (lan & 7)) << 3));
                }
            }
            if (t == ch) {   // diagonal tile (only ever in group 1)
                const int kBase = t * 64;
                #pragma unroll
                for (int nt = 0; nt < 4; ++nt)
                    #pragma unroll
                    for (int reg = 0; reg < 4; ++reg)
                        if (kBase + nt * 16 + quad * 4 + reg > qAbs)
                            scCur[nt][reg] = -INFINITY;
            }
            float mx = scCur[0][0];
            #pragma unroll
            for (int nt = 0; nt < 4; ++nt)
                #pragma unroll
                for (int reg = 0; reg < 4; ++reg) mx = fmaxf(mx, scCur[nt][reg]);
            mx = fmaxf(mx, __shfl_xor(mx, 16, 64));
            mx = fmaxf(mx, __shfl_xor(mx, 32, 64));
            const float mnew = fmaxf(mrow, mx);
            if (!__all(mx <= mrow)) {
                const float alpha = exp2f(mrow - mnew);
                l_acc[0] *= alpha;
                #pragma unroll
                for (int tt = 0; tt < 4; ++tt)
                    #pragma unroll
                    for (int ii = 0; ii < 4; ++ii) o[tt][ii] *= alpha;
            }
            mrow = mnew;
            bf16x4 pb[4];
            #pragma unroll
            for (int nt = 0; nt < 4; ++nt)
                #pragma unroll
                for (int reg = 0; reg < 4; ++reg)
                    pb[nt][reg] = static_cast<__bf16>(exp2f(scCur[nt][reg] - mnew));
            #pragma unroll
            for (int nt = 0; nt < 4; ++nt)
                l_acc = mfma_pv(ones, pb[nt], l_acc);
            #pragma unroll
            for (int tt = 0; tt < 4; ++tt)
                #pragma unroll
                for (int nt = 0; nt < 4; ++nt)
                    o[tt] = mfma_pv(Vfv[tt][nt], pb[nt], o[tt]);
            if (i + 1 < cg) {
                #pragma unroll
                for (int nt = 0; nt < 4; ++nt) scCur[nt] = scNext[nt];
            }
        }
    }
    #undef STAGE_K
    #undef STAGE_V
    #undef QK_TILE

    // ---- combine the two k-halves (LDS scratch reuses staging buffers) ----
    __syncthreads();   // all LDS reads done; all DMA drained (guards)
    float* scr = (float*)&ldsBuf[0][0][0][0];   // 36KB used of 64KB
    float* s = scr + (int)threadIdx.x * 18;
    s[0] = mrow;
    s[1] = l_acc[0];
    #pragma unroll
    for (int t = 0; t < 4; ++t)
        #pragma unroll
        for (int reg = 0; reg < 4; ++reg) s[2 + t * 4 + reg] = o[t][reg];
    __syncthreads();
    if (grp == 0) {
        const float* p = scr + ((int)threadIdx.x + 256) * 18;
        const float m1 = p[0], l1 = p[1];
        const float m = fmaxf(mrow, m1);
        const float a0 = exp2f(mrow - m);
        const float a1 = exp2f(m1 - m);
        const float rl = 1.f / (l_acc[0] * a0 + l1 * a1);
        #pragma unroll
        for (int t = 0; t < 4; ++t) {
            bf16x4 ob;
            #pragma unroll
            for (int reg = 0; reg < 4; ++reg)
                ob[reg] = static_cast<__bf16>(
                    (o[t][reg] * a0 + p[2 + t * 4 + reg] * a1) * rl);
            *(bf16x4*)(attn + ((size_t)bn * SS_ + qAbs) * 64 + t * 16 + quad * 4) = ob;
        }
    }
}

// ---------- K3: output projection (R17 exact: BM=64/BN=128, 256 thr) ----------
__global__ __launch_bounds__(256) void out_m97_kernel(
    const unsigned short* __restrict__ attn,
    const unsigned short* __restrict__ WOt,
    float* __restrict__ out)
{
    __shared__ unsigned short As[64 * 64];
    __shared__ unsigned short Bs[128 * 64];
    const int tid = threadIdx.x;
    const int l = tid & 63, w = tid >> 6;
    const int quad = l >> 4, lan = l & 15;
    const int mBase = blockIdx.x * 64;
    const int nBase = blockIdx.y * 128;
    const int wm = (w & 1) * 32, wn = (w >> 1) * 64;
    const int bbU = mBase >> 11;
    const int ssBase = mBase & 2047;

    floatx4 acc[2][4];
    #pragma unroll
    for (int a = 0; a < 2; ++a)
        #pragma unroll
        for (int b = 0; b < 4; ++b)
            #pragma unroll
            for (int i = 0; i < 4; ++i) acc[a][b][i] = 0.f;

    const int sr = l >> 3;
    const int sgx = ((l & 7) ^ sr) * 8;

    for (int kt = 0; kt < 16; ++kt) {
        const int k0 = kt * 64;
        __syncthreads();
        #pragma unroll
        for (int i = 0; i < 2; ++i) {
            const int row = i * 32 + w * 8 + sr;
            gl_lds16(attn + ((size_t)(bbU * NH_ + kt) * SS_ + ssBase + row) * 64 + sgx,
                     As + i * 2048 + w * 512);
        }
        #pragma unroll
        for (int i = 0; i < 4; ++i) {
            const int row = i * 32 + w * 8 + sr;
            gl_lds16(WOt + (size_t)(nBase + row) * DD_ + k0 + sgx,
                     Bs + i * 2048 + w * 512);
        }
        __syncthreads();
        #pragma unroll
        for (int ks = 0; ks < 2; ++ks) {
            const int fo = (((ks * 4 + quad) ^ (lan & 7)) << 3);
            bf16x8 a[2], b[4];
            #pragma unroll
            for (int mi = 0; mi < 2; ++mi)
                a[mi] = *(const bf16x8*)(As + (wm + mi * 16 + lan) * 64 + fo);
            #pragma unroll
            for (int ni = 0; ni < 4; ++ni)
                b[ni] = *(const bf16x8*)(Bs + (wn + ni * 16 + lan) * 64 + fo);
            #pragma unroll
            for (int mi = 0; mi < 2; ++mi)
                #pragma unroll
                for (int ni = 0; ni < 4; ++ni)
                    acc[mi][ni] = __builtin_amdgcn_mfma_f32_16x16x32_bf16(
                        a[mi], b[ni], acc[mi][ni], 0, 0, 0);
        }
    }
    #pragma unroll
    for (int mi = 0; mi < 2; ++mi)
        #pragma unroll
        for (int ni = 0; ni < 4; ++ni)
            #pragma unroll
            for (int reg = 0; reg < 4; ++reg) {
                int m = mBase + wm + mi * 16 + quad * 4 + reg;
                out[(size_t)m * DD_ + nBase + wn + ni * 16 + lan] = acc[mi][ni][reg];
            }
}

extern "C" void kernel_launch(void* const* d_in, const int* in_sizes, int n_in,
                              void* d_out, int out_size, void* d_ws, size_t ws_size,
                              hipStream_t stream) {
    const float* resid = (const float*)d_in[0];
    const float* WQ    = (const float*)d_in[1];
    const float* WK    = (const float*)d_in[2];
    const float* WV    = (const float*)d_in[3];
    const float* WO    = (const float*)d_in[4];
    float* out = (float*)d_out;

    unsigned short* q      = (unsigned short*)d_ws;
    unsigned short* kk     = q      + 4194304;
    unsigned short* vT     = kk     + 4194304;
    unsigned short* attn   = vT     + 4194304;
    unsigned short* residB = attn   + 4194304;
    unsigned short* WQb    = residB + 4194304;
    unsigned short* WKb    = WQb    + 1048576;
    unsigned short* WVb    = WKb    + 1048576;
    unsigned short* WOt    = WVb    + 1048576;

    cast_bf16_kernel<<<dim3(7168), 256, 0, stream>>>(
        resid, WQ, WK, WV, residB, WQb, WKb, WVb);
    wo_transpose_kernel<<<dim3(16, 16), 256, 0, stream>>>(WO, WOt);
    qkv_fused_kernel<<<dim3(32, 16), 512, 0, stream>>>(
        residB, WQb, WKb, WVb, q, kk, vT);
    flash_mfma_kernel<<<dim3(1024), dim3(512), 0, stream>>>(q, kk, vT, attn);
    out_m97_kernel<<<dim3(64, 8), 256, 0, stream>>>(attn, WOt, out);
}

// Round 13
// 186.303 us; speedup vs baseline: 1.0462x; 1.0462x over previous
//
#include <hip/hip_runtime.h>
#include <math.h>

// R22: CROSS-BLOCK split-K flash. R21 post-mortem: in-block split convoyed
// 8 waves at one barrier + dropped to 2 blk/CU -> 73us. But R20's numbers
// validated the model: flash = longest block chain = 33 iters x 3800cy =
// 52.3us (matches 52.4 measured). R22 splits the chain ACROSS blocks:
// grid 2048, each (bn,chunk) covered by two independent 256-thr blocks
// (halves of the k-range), each running the R20-exact loop body (4 waves,
// 32KB LDS, no new coupling). Partials (O bf16 unnorm, m/l fp32) land in
// DEAD ws regions (pO0=residB, pO1=attn in-place, ml=WQb — all dead after
// qkv; zero ws growth). combine_kernel (256 blocks) merges. Empty half
// (ch=0): m=-inf -> weight 0, no NaN. No dangling DMA (R20 guards).
// GEMMs: R17 exact. Kill criterion: flash >=45us => model wrong, stop.
// Layouts (verified R2-R21, absmax 7.8e-3):
//   x32 A-frag: m=lane&15, k=(lane>>4)*8+j ; B-frag: n=lane&15, k=(lane>>4)*8+j
//   x16 A/B-frag: idx=lane&15, k=(lane>>4)*4+j
//   C/D (all 16x16): col=lane&15, row=(lane>>4)*4+reg

#define SS_ 2048
#define DD_ 1024
#define NH_ 16
#define BN_ 32
#define BS_ 4096

typedef __bf16 bf16x8 __attribute__((ext_vector_type(8)));
typedef __bf16 bf16x4 __attribute__((ext_vector_type(4)));
typedef short shortx4 __attribute__((ext_vector_type(4)));
typedef float floatx4 __attribute__((ext_vector_type(4)));
typedef unsigned short ushortx4 __attribute__((ext_vector_type(4)));

__device__ __forceinline__ unsigned short f2bf(float f) {
    union { float f; unsigned u; } v; v.f = f;
    unsigned r = v.u + 0x7FFFu + ((v.u >> 16) & 1u);   // RNE
    return (unsigned short)(r >> 16);
}

__device__ __forceinline__ floatx4 mfma_pv(bf16x4 a, bf16x4 b, floatx4 c) {
#if __has_builtin(__builtin_amdgcn_mfma_f32_16x16x16_bf16)
    return __builtin_amdgcn_mfma_f32_16x16x16_bf16(a, b, c, 0, 0, 0);
#else
    return __builtin_amdgcn_mfma_f32_16x16x16bf16_1k(
        __builtin_bit_cast(shortx4, a), __builtin_bit_cast(shortx4, b), c, 0, 0, 0);
#endif
}

__device__ __forceinline__ void gl_lds16(const unsigned short* g, unsigned short* l) {
    __builtin_amdgcn_global_load_lds(
        (const __attribute__((address_space(1))) unsigned int*)g,
        (__attribute__((address_space(3))) unsigned int*)l, 16, 0, 0);
}

// ---------- K0a: cast resid + WQ/WK/WV to bf16 (1D grid) ----------
__global__ __launch_bounds__(256) void cast_bf16_kernel(
    const float* __restrict__ resid, const float* __restrict__ WQ,
    const float* __restrict__ WK, const float* __restrict__ WV,
    unsigned short* __restrict__ residB, unsigned short* __restrict__ WQb,
    unsigned short* __restrict__ WKb, unsigned short* __restrict__ WVb)
{
    const int x = blockIdx.x;
    int z, ix;
    if (x < 4096) { z = 0; ix = x; }
    else { z = 1 + ((x - 4096) >> 10); ix = (x - 4096) & 1023; }
    const float* src = (z == 0) ? resid : (z == 1) ? WQ : (z == 2) ? WK : WV;
    unsigned short* dst = (z == 0) ? residB : (z == 1) ? WQb : (z == 2) ? WKb : WVb;
    const int i = (ix * 256 + threadIdx.x) * 4;
    float4 f = *(const float4*)(src + i);
    ushortx4 o;
    o[0] = f2bf(f.x); o[1] = f2bf(f.y); o[2] = f2bf(f.z); o[3] = f2bf(f.w);
    *(ushortx4*)(dst + i) = o;
}

// ---------- K0b: WO [kk=n*64+h][d] fp32 -> WOt [d][kk] bf16 ----------
__global__ __launch_bounds__(256) void wo_transpose_kernel(
    const float* __restrict__ WO, unsigned short* __restrict__ WOt)
{
    __shared__ float t[64][65];
    const int kk0 = blockIdx.x * 64, d0 = blockIdx.y * 64;
    #pragma unroll
    for (int it = 0; it < 16; ++it) {
        int idx = it * 256 + threadIdx.x;
        int r = idx >> 6, c = idx & 63;
        t[r][c] = WO[(kk0 + r) * DD_ + d0 + c];
    }
    __syncthreads();
    #pragma unroll
    for (int it = 0; it < 16; ++it) {
        int idx = it * 256 + threadIdx.x;
        int r = idx >> 6, c = idx & 63;
        WOt[(d0 + r) * DD_ + kk0 + c] = f2bf(t[c][r]);
    }
}

// ---------- K1: FUSED QKV GEMM (R17 exact: BM=128, BN=64, 512 thr) ----------
__global__ __launch_bounds__(512, 4) void qkv_fused_kernel(
    const unsigned short* __restrict__ residB,
    const unsigned short* __restrict__ WQb,
    const unsigned short* __restrict__ WKb,
    const unsigned short* __restrict__ WVb,
    unsigned short* __restrict__ q, unsigned short* __restrict__ kk,
    unsigned short* __restrict__ vT)
{
    __shared__ unsigned short As[128 * 64];
    __shared__ unsigned short Bq[64 * 64];
    __shared__ unsigned short Bk[64 * 64];
    __shared__ unsigned short Bv[64 * 64];
    const int tid = threadIdx.x;
    const int l = tid & 63, w = tid >> 6;          // w: 0..7
    const int quad = l >> 4, lan = l & 15;
    const int mBase = blockIdx.x * 128;
    const int head = blockIdx.y;                   // BN=64 == one head
    const int nBase = head * 64;

    floatx4 accQ[4], accK[4], accV[4];
    #pragma unroll
    for (int ni = 0; ni < 4; ++ni)
        #pragma unroll
        for (int i = 0; i < 4; ++i) {
            accQ[ni][i] = 0.f; accK[ni][i] = 0.f; accV[ni][i] = 0.f;
        }

    const int sr = l >> 3;
    const int sgx = ((l & 7) ^ sr) * 8;

    for (int k0 = 0; k0 < DD_; k0 += 64) {
        __syncthreads();
        gl_lds16(residB + (size_t)(mBase + w * 16 + sr) * DD_ + k0 + sgx,
                 As + (w * 16) * 64);
        gl_lds16(residB + (size_t)(mBase + w * 16 + 8 + sr) * DD_ + k0 + sgx,
                 As + (w * 16 + 8) * 64);
        gl_lds16(WQb + (size_t)(nBase + w * 8 + sr) * DD_ + k0 + sgx,
                 Bq + (w * 8) * 64);
        gl_lds16(WKb + (size_t)(nBase + w * 8 + sr) * DD_ + k0 + sgx,
                 Bk + (w * 8) * 64);
        gl_lds16(WVb + (size_t)(nBase + w * 8 + sr) * DD_ + k0 + sgx,
                 Bv + (w * 8) * 64);
        __syncthreads();
        #pragma unroll
        for (int ks = 0; ks < 2; ++ks) {
            const int fo = (((ks * 4 + quad) ^ (lan & 7)) << 3);
            bf16x8 a = *(const bf16x8*)(As + (w * 16 + lan) * 64 + fo);
            bf16x8 bq[4], bk[4], bv[4];
            #pragma unroll
            for (int ni = 0; ni < 4; ++ni) {
                bq[ni] = *(const bf16x8*)(Bq + (ni * 16 + lan) * 64 + fo);
                bk[ni] = *(const bf16x8*)(Bk + (ni * 16 + lan) * 64 + fo);
                bv[ni] = *(const bf16x8*)(Bv + (ni * 16 + lan) * 64 + fo);
            }
            #pragma unroll
            for (int ni = 0; ni < 4; ++ni) {
                accQ[ni] = __builtin_amdgcn_mfma_f32_16x16x32_bf16(a, bq[ni], accQ[ni], 0, 0, 0);
                accK[ni] = __builtin_amdgcn_mfma_f32_16x16x32_bf16(a, bk[ni], accK[ni], 0, 0, 0);
                accV[ni] = __builtin_amdgcn_mfma_f32_16x16x32_bf16(a, bv[ni], accV[ni], 0, 0, 0);
            }
        }
    }
    const int m0 = mBase + w * 16 + quad * 4;
    const int bb = m0 >> 11, ss0 = m0 & 2047;
    const float scl = 0.125f * 1.44269504088896340736f;
    #pragma unroll
    for (int ni = 0; ni < 4; ++ni) {
        const int h = ni * 16 + lan;
        bf16x4 obq, obv;
        #pragma unroll
        for (int reg = 0; reg < 4; ++reg) {
            obq[reg] = static_cast<__bf16>(accQ[ni][reg] * scl);
            obv[reg] = static_cast<__bf16>(accV[ni][reg]);
        }
        *(bf16x4*)(q  + ((size_t)(bb * NH_ + head) * 64 + h) * SS_ + ss0) = obq;
        *(bf16x4*)(vT + ((size_t)(bb * NH_ + head) * 64 + h) * SS_ + ss0) = obv;
        #pragma unroll
        for (int reg = 0; reg < 4; ++reg)
            kk[((size_t)(bb * NH_ + head) * SS_ + ss0 + reg) * 64 + h] =
                f2bf(accK[ni][reg]);
    }
}

// ---------- K2: flash attention, cross-block split-K halves ----------
// grid 2048: f -> bn (low 5 bits, XCD-local), ch = 31-((f>>5)&31), half = f>>10.
// Each block: R20-exact loop over tiles [base, base+cnt). Writes partial.
__global__ __launch_bounds__(256, 4) void flash_mfma_kernel(
    const unsigned short* __restrict__ q,
    const unsigned short* __restrict__ k,
    const unsigned short* __restrict__ vT,
    unsigned short* __restrict__ pO0,    // residB region (dead after qkv)
    unsigned short* __restrict__ pO1,    // attn region (combine in-place)
    float* __restrict__ ml)              // WQb region: m0,l0,m1,l1 x 65536
{
    __shared__ unsigned short ldsK[2][64 * 64];
    __shared__ unsigned short ldsV[2][64 * 64];
    const int l = threadIdx.x & 63, w = threadIdx.x >> 6;   // w: 0..3
    const int quad = l >> 4, lan = l & 15;
    const int f = blockIdx.x;                               // 0..2047
    const int bn = (f & 7) | (((f >> 3) & 3) << 3);         // XCD swizzle
    const int ch = 31 - ((f >> 5) & 31);                    // heavy first
    const int half = f >> 10;                               // k-half
    const int hsz = (ch + 1) >> 1;
    const int base = half ? hsz : 0;
    const int cnt = half ? (ch + 1 - hsz) : hsz;            // may be 0 (ch=0,half=0)

    const unsigned short* Qg = q  + (size_t)bn * 64 * SS_;  // [h][s]
    const unsigned short* Kg = k  + (size_t)bn * SS_ * 64;  // [s][h]
    const unsigned short* Vg = vT + (size_t)bn * 64 * SS_;  // [h][s]

    const int srl = l >> 3;
    const int sgx = (l & 7) ^ srl;

    const int qAbs = ch * 64 + w * 16 + lan;

    bf16x8 Qf0, Qf1;
    #pragma unroll
    for (int j = 0; j < 8; ++j) {
        Qf0[j] = *(const __bf16*)(Qg + (size_t)(quad * 8 + j) * SS_ + qAbs);
        Qf1[j] = *(const __bf16*)(Qg + (size_t)(quad * 8 + j + 32) * SS_ + qAbs);
    }

    bf16x4 ones;
    #pragma unroll
    for (int i = 0; i < 4; ++i) ones[i] = static_cast<__bf16>(1.0f);

    float mrow = -INFINITY;
    floatx4 l_acc;
    floatx4 o[4];
    #pragma unroll
    for (int i = 0; i < 4; ++i) l_acc[i] = 0.f;
    #pragma unroll
    for (int t = 0; t < 4; ++t)
        #pragma unroll
        for (int i = 0; i < 4; ++i) o[t][i] = 0.f;

    #define STAGE_K(kt_, buf_)                                                  \
        { const int row0_ = w * 16, kB_ = (kt_) * 64;                           \
          gl_lds16(Kg + (size_t)(kB_ + row0_ + srl) * 64 + sgx * 8,             \
                   &ldsK[buf_][row0_ * 64]);                                    \
          gl_lds16(Kg + (size_t)(kB_ + row0_ + 8 + srl) * 64 + sgx * 8,         \
                   &ldsK[buf_][(row0_ + 8) * 64]); }
    #define STAGE_V(kt_, buf_)                                                  \
        { const int row0_ = w * 16, kB_ = (kt_) * 64;                           \
          gl_lds16(Vg + (size_t)(row0_ + srl) * SS_ + kB_ + sgx * 8,            \
                   &ldsV[buf_][row0_ * 64]);                                    \
          gl_lds16(Vg + (size_t)(row0_ + 8 + srl) * SS_ + kB_ + sgx * 8,        \
                   &ldsV[buf_][(row0_ + 8) * 64]); }
    #define QK_TILE(dst_, buf_)                                                 \
        { const unsigned short* Kb_ = &ldsK[buf_][0];                           \
          bf16x8 K0v_[4], K1v_[4];                                              \
          _Pragma("unroll")                                                     \
          for (int nt = 0; nt < 4; ++nt) {                                      \
              const unsigned short* kr_ = Kb_ + (nt * 16 + lan) * 64;           \
              K0v_[nt] = *(const bf16x8*)(kr_ + ((quad ^ (lan & 7)) << 3));     \
              K1v_[nt] = *(const bf16x8*)(kr_ + (((quad + 4) ^ (lan & 7)) << 3)); } \
          _Pragma("unroll")                                                     \
          for (int nt = 0; nt < 4; ++nt) {                                      \
              floatx4 zz_; zz_[0] = zz_[1] = zz_[2] = zz_[3] = 0.f;             \
              dst_[nt] = __builtin_amdgcn_mfma_f32_16x16x32_bf16(K0v_[nt], Qf0, zz_, 0, 0, 0); \
              dst_[nt] = __builtin_amdgcn_mfma_f32_16x16x32_bf16(K1v_[nt], Qf1, dst_[nt], 0, 0, 0); } }

    // prologue (uniform within block; cnt==0 blocks skip staging/loop)
    if (cnt >= 1) { STAGE_K(base, 0); STAGE_V(base, 0); }
    __syncthreads();
    if (cnt >= 2) STAGE_K(base + 1, 1);
    floatx4 scCur[4], scNext[4];
    if (cnt >= 1) QK_TILE(scCur, 0);

    for (int i = 0; i < cnt; ++i) {
        const int t = base + i;
        __syncthreads();   // stage(i+1) visible; prior readers drained
        if (i + 2 < cnt) STAGE_K(base + i + 2, (i + 2) & 1);
        if (i + 1 < cnt) {
            STAGE_V(base + i + 1, (i + 1) & 1);
            QK_TILE(scNext, (i + 1) & 1);
        }
        // batched V reads for tile t (parity i&1); latency hides under softmax
        const unsigned short* Vb = &ldsV[i & 1][0];
        bf16x4 Vfv[4][4];
        #pragma unroll
        for (int tt = 0; tt < 4; ++tt) {
            const unsigned short* vr = Vb + (tt * 16 + lan) * 64 + ((quad & 1) << 2);
            #pragma unroll
            for (int nt = 0; nt < 4; ++nt) {
                const int g2 = nt * 2 + (quad >> 1);
                Vfv[tt][nt] = *(const bf16x4*)(vr + ((g2 ^ (lan & 7)) << 3));
            }
        }
        if (t == ch) {   // diagonal tile (only in half 1)
            const int kBase = t * 64;
            #pragma unroll
            for (int nt = 0; nt < 4; ++nt)
                #pragma unroll
                for (int reg = 0; reg < 4; ++reg)
                    if (kBase + nt * 16 + quad * 4 + reg > qAbs)
                        scCur[nt][reg] = -INFINITY;
        }
        float mx = scCur[0][0];
        #pragma unroll
        for (int nt = 0; nt < 4; ++nt)
            #pragma unroll
            for (int reg = 0; reg < 4; ++reg) mx = fmaxf(mx, scCur[nt][reg]);
        mx = fmaxf(mx, __shfl_xor(mx, 16, 64));
        mx = fmaxf(mx, __shfl_xor(mx, 32, 64));
        const float mnew = fmaxf(mrow, mx);
        if (!__all(mx <= mrow)) {
            const float alpha = exp2f(mrow - mnew);
            l_acc[0] *= alpha;
            #pragma unroll
            for (int tt = 0; tt < 4; ++tt)
                #pragma unroll
                for (int ii = 0; ii < 4; ++ii) o[tt][ii] *= alpha;
        }
        mrow = mnew;
        bf16x4 pb[4];
        #pragma unroll
        for (int nt = 0; nt < 4; ++nt)
            #pragma unroll
            for (int reg = 0; reg < 4; ++reg)
                pb[nt][reg] = static_cast<__bf16>(exp2f(scCur[nt][reg] - mnew));
        #pragma unroll
        for (int nt = 0; nt < 4; ++nt)
            l_acc = mfma_pv(ones, pb[nt], l_acc);
        #pragma unroll
        for (int tt = 0; tt < 4; ++tt)
            #pragma unroll
            for (int nt = 0; nt < 4; ++nt)
                o[tt] = mfma_pv(Vfv[tt][nt], pb[nt], o[tt]);
        if (i + 1 < cnt) {
            #pragma unroll
            for (int nt = 0; nt < 4; ++nt) scCur[nt] = scNext[nt];
        }
    }
    #undef STAGE_K
    #undef STAGE_V
    #undef QK_TILE

    // ---- write unnormalized partial (registers -> global; no LDS, no DMA) ----
    unsigned short* pO = half ? pO1 : pO0;
    const size_t rbase = ((size_t)bn * SS_ + qAbs) * 64;
    #pragma unroll
    for (int t = 0; t < 4; ++t) {
        bf16x4 ob;
        #pragma unroll
        for (int reg = 0; reg < 4; ++reg)
            ob[reg] = static_cast<__bf16>(o[t][reg]);
        *(bf16x4*)(pO + rbase + t * 16 + quad * 4) = ob;
    }
    if (quad == 0) {
        float* M = ml + half * 131072;
        M[bn * SS_ + qAbs] = mrow;            // m
        M[65536 + bn * SS_ + qAbs] = l_acc[0]; // l
    }
}

// ---------- K2b: combine the two k-half partials (in-place into attn) ----------
__global__ __launch_bounds__(256) void combine_kernel(
    const unsigned short* __restrict__ pO0,
    unsigned short* __restrict__ attn,    // == pO1
    const float* __restrict__ ml)
{
    const int r = blockIdx.x * 256 + threadIdx.x;   // 0..65535 = bn*2048+row
    const float m0 = ml[r],          l0 = ml[65536 + r];
    const float m1 = ml[131072 + r], l1 = ml[196608 + r];
    const float m = fmaxf(m0, m1);
    const float a0 = exp2f(m0 - m), a1 = exp2f(m1 - m);   // exp2(-inf)=0
    const float rl = 1.f / (l0 * a0 + l1 * a1);
    const size_t bo = (size_t)r * 64;
    #pragma unroll
    for (int j = 0; j < 8; ++j) {
        bf16x8 v0 = *(const bf16x8*)(pO0 + bo + j * 8);
        bf16x8 v1 = *(const bf16x8*)(attn + bo + j * 8);
        bf16x8 ov;
        #pragma unroll
        for (int e = 0; e < 8; ++e)
            ov[e] = static_cast<__bf16>(
                ((float)v0[e] * a0 + (float)v1[e] * a1) * rl);
        *(bf16x8*)(attn + bo + j * 8) = ov;
    }
}

// ---------- K3: output projection (R17 exact: BM=64/BN=128, 256 thr) ----------
__global__ __launch_bounds__(256) void out_m97_kernel(
    const unsigned short* __restrict__ attn,
    const unsigned short* __restrict__ WOt,
    float* __restrict__ out)
{
    __shared__ unsigned short As[64 * 64];
    __shared__ unsigned short Bs[128 * 64];
    const int tid = threadIdx.x;
    const int l = tid & 63, w = tid >> 6;
    const int quad = l >> 4, lan = l & 15;
    const int mBase = blockIdx.x * 64;
    const int nBase = blockIdx.y * 128;
    const int wm = (w & 1) * 32, wn = (w >> 1) * 64;
    const int bbU = mBase >> 11;
    const int ssBase = mBase & 2047;

    floatx4 acc[2][4];
    #pragma unroll
    for (int a = 0; a < 2; ++a)
        #pragma unroll
        for (int b = 0; b < 4; ++b)
            #pragma unroll
            for (int i = 0; i < 4; ++i) acc[a][b][i] = 0.f;

    const int sr = l >> 3;
    const int sgx = ((l & 7) ^ sr) * 8;

    for (int kt = 0; kt < 16; ++kt) {
        const int k0 = kt * 64;
        __syncthreads();
        #pragma unroll
        for (int i = 0; i < 2; ++i) {
            const int row = i * 32 + w * 8 + sr;
            gl_lds16(attn + ((size_t)(bbU * NH_ + kt) * SS_ + ssBase + row) * 64 + sgx,
                     As + i * 2048 + w * 512);
        }
        #pragma unroll
        for (int i = 0; i < 4; ++i) {
            const int row = i * 32 + w * 8 + sr;
            gl_lds16(WOt + (size_t)(nBase + row) * DD_ + k0 + sgx,
                     Bs + i * 2048 + w * 512);
        }
        __syncthreads();
        #pragma unroll
        for (int ks = 0; ks < 2; ++ks) {
            const int fo = (((ks * 4 + quad) ^ (lan & 7)) << 3);
            bf16x8 a[2], b[4];
            #pragma unroll
            for (int mi = 0; mi < 2; ++mi)
                a[mi] = *(const bf16x8*)(As + (wm + mi * 16 + lan) * 64 + fo);
            #pragma unroll
            for (int ni = 0; ni < 4; ++ni)
                b[ni] = *(const bf16x8*)(Bs + (wn + ni * 16 + lan) * 64 + fo);
            #pragma unroll
            for (int mi = 0; mi < 2; ++mi)
                #pragma unroll
                for (int ni = 0; ni < 4; ++ni)
                    acc[mi][ni] = __builtin_amdgcn_mfma_f32_16x16x32_bf16(
                        a[mi], b[ni], acc[mi][ni], 0, 0, 0);
        }
    }
    #pragma unroll
    for (int mi = 0; mi < 2; ++mi)
        #pragma unroll
        for (int ni = 0; ni < 4; ++ni)
            #pragma unroll
            for (int reg = 0; reg < 4; ++reg) {
                int m = mBase + wm + mi * 16 + quad * 4 + reg;
                out[(size_t)m * DD_ + nBase + wn + ni * 16 + lan] = acc[mi][ni][reg];
            }
}

extern "C" void kernel_launch(void* const* d_in, const int* in_sizes, int n_in,
                              void* d_out, int out_size, void* d_ws, size_t ws_size,
                              hipStream_t stream) {
    const float* resid = (const float*)d_in[0];
    const float* WQ    = (const float*)d_in[1];
    const float* WK    = (const float*)d_in[2];
    const float* WV    = (const float*)d_in[3];
    const float* WO    = (const float*)d_in[4];
    float* out = (float*)d_out;

    unsigned short* q      = (unsigned short*)d_ws;
    unsigned short* kk     = q      + 4194304;
    unsigned short* vT     = kk     + 4194304;
    unsigned short* attn   = vT     + 4194304;   // pO1 + final attn
    unsigned short* residB = attn   + 4194304;   // pO0 after qkv
    unsigned short* WQb    = residB + 4194304;   // ml after qkv
    unsigned short* WKb    = WQb    + 1048576;
    unsigned short* WVb    = WKb    + 1048576;
    unsigned short* WOt    = WVb    + 1048576;

    cast_bf16_kernel<<<dim3(7168), 256, 0, stream>>>(
        resid, WQ, WK, WV, residB, WQb, WKb, WVb);
    wo_transpose_kernel<<<dim3(16, 16), 256, 0, stream>>>(WO, WOt);
    qkv_fused_kernel<<<dim3(32, 16), 512, 0, stream>>>(
        residB, WQb, WKb, WVb, q, kk, vT);
    flash_mfma_kernel<<<dim3(2048), dim3(256), 0, stream>>>(
        q, kk, vT, residB /*pO0*/, attn /*pO1*/, (float*)WQb /*ml*/);
    combine_kernel<<<dim3(256), dim3(256), 0, stream>>>(
        residB, attn, (const float*)WQb);
    out_m97_kernel<<<dim3(64, 8), 256, 0, stream>>>(attn, WOt, out);
}

// Round 14
// 173.179 us; speedup vs baseline: 1.1255x; 1.0758x over previous
//
#include <hip/hip_runtime.h>
#include <math.h>

// R23: consolidation. R22 post-mortem: cross-block split-K left flash at
// 56us with HALF the per-block chain -> flash is aggregate-throughput
// bound on per-tile-iter cost (8th falsified flash-scheduling theory);
// split-K only added partial traffic. Also proven: qkv tile space is
// Pareto-exhausted at R17's BM=128/BN=64 (staged bytes 8192/BN+3BN MB,
// min at BN=64). R23 = best-known everything: R17 GEMMs exact, R20 flash
// exact (52.4us, K-dbuf 32KB), cast+wo_transpose merged into ONE dispatch
// (saves one graph-replay launch slot).
// Layouts (verified R2-R22, absmax 7.8e-3):
//   x32 A-frag: m=lane&15, k=(lane>>4)*8+j ; B-frag: n=lane&15, k=(lane>>4)*8+j
//   x16 A/B-frag: idx=lane&15, k=(lane>>4)*4+j
//   C/D (all 16x16): col=lane&15, row=(lane>>4)*4+reg

#define SS_ 2048
#define DD_ 1024
#define NH_ 16
#define BN_ 32
#define BS_ 4096

typedef __bf16 bf16x8 __attribute__((ext_vector_type(8)));
typedef __bf16 bf16x4 __attribute__((ext_vector_type(4)));
typedef short shortx4 __attribute__((ext_vector_type(4)));
typedef float floatx4 __attribute__((ext_vector_type(4)));
typedef unsigned short ushortx4 __attribute__((ext_vector_type(4)));

__device__ __forceinline__ unsigned short f2bf(float f) {
    union { float f; unsigned u; } v; v.f = f;
    unsigned r = v.u + 0x7FFFu + ((v.u >> 16) & 1u);   // RNE
    return (unsigned short)(r >> 16);
}

__device__ __forceinline__ floatx4 mfma_pv(bf16x4 a, bf16x4 b, floatx4 c) {
#if __has_builtin(__builtin_amdgcn_mfma_f32_16x16x16_bf16)
    return __builtin_amdgcn_mfma_f32_16x16x16_bf16(a, b, c, 0, 0, 0);
#else
    return __builtin_amdgcn_mfma_f32_16x16x16bf16_1k(
        __builtin_bit_cast(shortx4, a), __builtin_bit_cast(shortx4, b), c, 0, 0, 0);
#endif
}

__device__ __forceinline__ void gl_lds16(const unsigned short* g, unsigned short* l) {
    __builtin_amdgcn_global_load_lds(
        (const __attribute__((address_space(1))) unsigned int*)g,
        (__attribute__((address_space(3))) unsigned int*)l, 16, 0, 0);
}

// ---------- K0: cast resid/WQ/WK/WV to bf16 AND transpose WO (merged) ----------
// x < 7168: cast path. x >= 7168: wo-transpose path (256 blocks of 64x64).
__global__ __launch_bounds__(256) void prep_kernel(
    const float* __restrict__ resid, const float* __restrict__ WQ,
    const float* __restrict__ WK, const float* __restrict__ WV,
    const float* __restrict__ WO,
    unsigned short* __restrict__ residB, unsigned short* __restrict__ WQb,
    unsigned short* __restrict__ WKb, unsigned short* __restrict__ WVb,
    unsigned short* __restrict__ WOt)
{
    const int x = blockIdx.x;
    if (x < 7168) {
        int z, ix;
        if (x < 4096) { z = 0; ix = x; }
        else { z = 1 + ((x - 4096) >> 10); ix = (x - 4096) & 1023; }
        const float* src = (z == 0) ? resid : (z == 1) ? WQ : (z == 2) ? WK : WV;
        unsigned short* dst = (z == 0) ? residB : (z == 1) ? WQb : (z == 2) ? WKb : WVb;
        const int i = (ix * 256 + threadIdx.x) * 4;
        float4 f = *(const float4*)(src + i);
        ushortx4 o;
        o[0] = f2bf(f.x); o[1] = f2bf(f.y); o[2] = f2bf(f.z); o[3] = f2bf(f.w);
        *(ushortx4*)(dst + i) = o;
    } else {
        __shared__ float t[64][65];
        const int b = x - 7168;                  // 0..255
        const int kk0 = (b >> 4) * 64, d0 = (b & 15) * 64;
        #pragma unroll
        for (int it = 0; it < 16; ++it) {
            int idx = it * 256 + threadIdx.x;
            int r = idx >> 6, c = idx & 63;
            t[r][c] = WO[(kk0 + r) * DD_ + d0 + c];
        }
        __syncthreads();
        #pragma unroll
        for (int it = 0; it < 16; ++it) {
            int idx = it * 256 + threadIdx.x;
            int r = idx >> 6, c = idx & 63;
            WOt[(d0 + r) * DD_ + kk0 + c] = f2bf(t[c][r]);
        }
    }
}

// ---------- K1: FUSED QKV GEMM (R17 exact: BM=128, BN=64, 512 thr) ----------
__global__ __launch_bounds__(512, 4) void qkv_fused_kernel(
    const unsigned short* __restrict__ residB,
    const unsigned short* __restrict__ WQb,
    const unsigned short* __restrict__ WKb,
    const unsigned short* __restrict__ WVb,
    unsigned short* __restrict__ q, unsigned short* __restrict__ kk,
    unsigned short* __restrict__ vT)
{
    __shared__ unsigned short As[128 * 64];
    __shared__ unsigned short Bq[64 * 64];
    __shared__ unsigned short Bk[64 * 64];
    __shared__ unsigned short Bv[64 * 64];
    const int tid = threadIdx.x;
    const int l = tid & 63, w = tid >> 6;          // w: 0..7
    const int quad = l >> 4, lan = l & 15;
    const int mBase = blockIdx.x * 128;
    const int head = blockIdx.y;                   // BN=64 == one head
    const int nBase = head * 64;

    floatx4 accQ[4], accK[4], accV[4];
    #pragma unroll
    for (int ni = 0; ni < 4; ++ni)
        #pragma unroll
        for (int i = 0; i < 4; ++i) {
            accQ[ni][i] = 0.f; accK[ni][i] = 0.f; accV[ni][i] = 0.f;
        }

    const int sr = l >> 3;
    const int sgx = ((l & 7) ^ sr) * 8;

    for (int k0 = 0; k0 < DD_; k0 += 64) {
        __syncthreads();
        gl_lds16(residB + (size_t)(mBase + w * 16 + sr) * DD_ + k0 + sgx,
                 As + (w * 16) * 64);
        gl_lds16(residB + (size_t)(mBase + w * 16 + 8 + sr) * DD_ + k0 + sgx,
                 As + (w * 16 + 8) * 64);
        gl_lds16(WQb + (size_t)(nBase + w * 8 + sr) * DD_ + k0 + sgx,
                 Bq + (w * 8) * 64);
        gl_lds16(WKb + (size_t)(nBase + w * 8 + sr) * DD_ + k0 + sgx,
                 Bk + (w * 8) * 64);
        gl_lds16(WVb + (size_t)(nBase + w * 8 + sr) * DD_ + k0 + sgx,
                 Bv + (w * 8) * 64);
        __syncthreads();
        #pragma unroll
        for (int ks = 0; ks < 2; ++ks) {
            const int fo = (((ks * 4 + quad) ^ (lan & 7)) << 3);
            bf16x8 a = *(const bf16x8*)(As + (w * 16 + lan) * 64 + fo);
            bf16x8 bq[4], bk[4], bv[4];
            #pragma unroll
            for (int ni = 0; ni < 4; ++ni) {
                bq[ni] = *(const bf16x8*)(Bq + (ni * 16 + lan) * 64 + fo);
                bk[ni] = *(const bf16x8*)(Bk + (ni * 16 + lan) * 64 + fo);
                bv[ni] = *(const bf16x8*)(Bv + (ni * 16 + lan) * 64 + fo);
            }
            #pragma unroll
            for (int ni = 0; ni < 4; ++ni) {
                accQ[ni] = __builtin_amdgcn_mfma_f32_16x16x32_bf16(a, bq[ni], accQ[ni], 0, 0, 0);
                accK[ni] = __builtin_amdgcn_mfma_f32_16x16x32_bf16(a, bk[ni], accK[ni], 0, 0, 0);
                accV[ni] = __builtin_amdgcn_mfma_f32_16x16x32_bf16(a, bv[ni], accV[ni], 0, 0, 0);
            }
        }
    }
    const int m0 = mBase + w * 16 + quad * 4;
    const int bb = m0 >> 11, ss0 = m0 & 2047;
    const float scl = 0.125f * 1.44269504088896340736f;
    #pragma unroll
    for (int ni = 0; ni < 4; ++ni) {
        const int h = ni * 16 + lan;
        bf16x4 obq, obv;
        #pragma unroll
        for (int reg = 0; reg < 4; ++reg) {
            obq[reg] = static_cast<__bf16>(accQ[ni][reg] * scl);
            obv[reg] = static_cast<__bf16>(accV[ni][reg]);
        }
        *(bf16x4*)(q  + ((size_t)(bb * NH_ + head) * 64 + h) * SS_ + ss0) = obq;
        *(bf16x4*)(vT + ((size_t)(bb * NH_ + head) * 64 + h) * SS_ + ss0) = obv;
        #pragma unroll
        for (int reg = 0; reg < 4; ++reg)
            kk[((size_t)(bb * NH_ + head) * SS_ + ss0 + reg) * 64 + h] =
                f2bf(accK[ni][reg]);
    }
}

// ---------- K2: flash attention (R20 exact: K double-buffered, 32KB LDS) ----------
__global__ __launch_bounds__(256, 4) void flash_mfma_kernel(
    const unsigned short* __restrict__ q,
    const unsigned short* __restrict__ k,
    const unsigned short* __restrict__ vT,
    unsigned short* __restrict__ attn)
{
    __shared__ unsigned short ldsK[2][64 * 64];
    __shared__ unsigned short ldsV[2][64 * 64];
    const int l = threadIdx.x & 63, w = threadIdx.x >> 6;   // w: 0..3
    const int quad = l >> 4, lan = l & 15;
    const int f = blockIdx.x;                               // 0..1023
    const int bn = (f & 7) | (((f >> 3) & 3) << 3);         // XCD swizzle
    const int g = f >> 5;                                   // 0..31
    const int ch = (g < 8) ? (31 - g)
                 : (g < 16) ? (g + 8)
                 : (g < 24) ? (15 - (g - 16))
                 : (g - 24);

    const unsigned short* Qg = q  + (size_t)bn * 64 * SS_;  // [h][s]
    const unsigned short* Kg = k  + (size_t)bn * SS_ * 64;  // [s][h]
    const unsigned short* Vg = vT + (size_t)bn * 64 * SS_;  // [h][s]

    const int srl = l >> 3;
    const int sgx = (l & 7) ^ srl;

    const int qAbs = ch * 64 + w * 16 + lan;

    bf16x8 Qf0, Qf1;
    #pragma unroll
    for (int j = 0; j < 8; ++j) {
        Qf0[j] = *(const __bf16*)(Qg + (size_t)(quad * 8 + j) * SS_ + qAbs);
        Qf1[j] = *(const __bf16*)(Qg + (size_t)(quad * 8 + j + 32) * SS_ + qAbs);
    }

    bf16x4 ones;
    #pragma unroll
    for (int i = 0; i < 4; ++i) ones[i] = static_cast<__bf16>(1.0f);

    float mrow = -INFINITY;
    floatx4 l_acc;
    floatx4 o[4];
    #pragma unroll
    for (int i = 0; i < 4; ++i) l_acc[i] = 0.f;
    #pragma unroll
    for (int t = 0; t < 4; ++t)
        #pragma unroll
        for (int i = 0; i < 4; ++i) o[t][i] = 0.f;

    #define STAGE_K(kt_, buf_)                                                  \
        { const int row0_ = w * 16, kB_ = (kt_) * 64;                           \
          gl_lds16(Kg + (size_t)(kB_ + row0_ + srl) * 64 + sgx * 8,             \
                   &ldsK[buf_][row0_ * 64]);                                    \
          gl_lds16(Kg + (size_t)(kB_ + row0_ + 8 + srl) * 64 + sgx * 8,         \
                   &ldsK[buf_][(row0_ + 8) * 64]); }
    #define STAGE_V(kt_, buf_)                                                  \
        { const int row0_ = w * 16, kB_ = (kt_) * 64;                           \
          gl_lds16(Vg + (size_t)(row0_ + srl) * SS_ + kB_ + sgx * 8,            \
                   &ldsV[buf_][row0_ * 64]);                                    \
          gl_lds16(Vg + (size_t)(row0_ + 8 + srl) * SS_ + kB_ + sgx * 8,        \
                   &ldsV[buf_][(row0_ + 8) * 64]); }
    #define QK_TILE(dst_, buf_)                                                 \
        { const unsigned short* Kb_ = &ldsK[buf_][0];                           \
          bf16x8 K0v_[4], K1v_[4];                                              \
          _Pragma("unroll")                                                     \
          for (int nt = 0; nt < 4; ++nt) {                                      \
              const unsigned short* kr_ = Kb_ + (nt * 16 + lan) * 64;           \
              K0v_[nt] = *(const bf16x8*)(kr_ + ((quad ^ (lan & 7)) << 3));     \
              K1v_[nt] = *(const bf16x8*)(kr_ + (((quad + 4) ^ (lan & 7)) << 3)); } \
          _Pragma("unroll")                                                     \
          for (int nt = 0; nt < 4; ++nt) {                                      \
              floatx4 zz_; zz_[0] = zz_[1] = zz_[2] = zz_[3] = 0.f;             \
              dst_[nt] = __builtin_amdgcn_mfma_f32_16x16x32_bf16(K0v_[nt], Qf0, zz_, 0, 0, 0); \
              dst_[nt] = __builtin_amdgcn_mfma_f32_16x16x32_bf16(K1v_[nt], Qf1, dst_[nt], 0, 0, 0); } }

    STAGE_K(0, 0);
    STAGE_V(0, 0);
    __syncthreads();
    if (ch >= 1) STAGE_K(1, 1);
    floatx4 scCur[4], scNext[4];
    QK_TILE(scCur, 0);

    for (int kt = 0; kt <= ch; ++kt) {
        const int kBase = kt * 64;
        __syncthreads();   // stage(kt+1) visible; prior readers drained
        if (kt + 2 <= ch) STAGE_K(kt + 2, (kt + 2) & 1);
        if (kt + 1 <= ch) {
            STAGE_V(kt + 1, (kt + 1) & 1);
            QK_TILE(scNext, (kt + 1) & 1);
        }
        const unsigned short* Vb = &ldsV[kt & 1][0];
        bf16x4 Vfv[4][4];
        #pragma unroll
        for (int t = 0; t < 4; ++t) {
            const unsigned short* vr = Vb + (t * 16 + lan) * 64 + ((quad & 1) << 2);
            #pragma unroll
            for (int nt = 0; nt < 4; ++nt) {
                const int g2 = nt * 2 + (quad >> 1);
                Vfv[t][nt] = *(const bf16x4*)(vr + ((g2 ^ (lan & 7)) << 3));
            }
        }
        if (kt == ch) {   // diagonal: mask k > q
            #pragma unroll
            for (int nt = 0; nt < 4; ++nt)
                #pragma unroll
                for (int reg = 0; reg < 4; ++reg)
                    if (kBase + nt * 16 + quad * 4 + reg > qAbs)
                        scCur[nt][reg] = -INFINITY;
        }
        float mx = scCur[0][0];
        #pragma unroll
        for (int nt = 0; nt < 4; ++nt)
            #pragma unroll
            for (int reg = 0; reg < 4; ++reg) mx = fmaxf(mx, scCur[nt][reg]);
        mx = fmaxf(mx, __shfl_xor(mx, 16, 64));
        mx = fmaxf(mx, __shfl_xor(mx, 32, 64));
        const float mnew = fmaxf(mrow, mx);
        if (!__all(mx <= mrow)) {
            const float alpha = exp2f(mrow - mnew);
            l_acc[0] *= alpha;
            #pragma unroll
            for (int t = 0; t < 4; ++t)
                #pragma unroll
                for (int i = 0; i < 4; ++i) o[t][i] *= alpha;
        }
        mrow = mnew;
        bf16x4 pb[4];
        #pragma unroll
        for (int nt = 0; nt < 4; ++nt)
            #pragma unroll
            for (int reg = 0; reg < 4; ++reg)
                pb[nt][reg] = static_cast<__bf16>(exp2f(scCur[nt][reg] - mnew));
        #pragma unroll
        for (int nt = 0; nt < 4; ++nt)
            l_acc = mfma_pv(ones, pb[nt], l_acc);
        #pragma unroll
        for (int t = 0; t < 4; ++t)
            #pragma unroll
            for (int nt = 0; nt < 4; ++nt)
                o[t] = mfma_pv(Vfv[t][nt], pb[nt], o[t]);
        #pragma unroll
        for (int nt = 0; nt < 4; ++nt) scCur[nt] = scNext[nt];
    }
    const float rl = 1.f / l_acc[0];
    #pragma unroll
    for (int t = 0; t < 4; ++t) {
        bf16x4 ob;
        #pragma unroll
        for (int reg = 0; reg < 4; ++reg)
            ob[reg] = static_cast<__bf16>(o[t][reg] * rl);
        *(bf16x4*)(attn + ((size_t)bn * SS_ + qAbs) * 64 + t * 16 + quad * 4) = ob;
    }
    #undef STAGE_K
    #undef STAGE_V
    #undef QK_TILE
}

// ---------- K3: output projection (R17 exact: BM=64/BN=128, 256 thr) ----------
__global__ __launch_bounds__(256) void out_m97_kernel(
    const unsigned short* __restrict__ attn,
    const unsigned short* __restrict__ WOt,
    float* __restrict__ out)
{
    __shared__ unsigned short As[64 * 64];
    __shared__ unsigned short Bs[128 * 64];
    const int tid = threadIdx.x;
    const int l = tid & 63, w = tid >> 6;
    const int quad = l >> 4, lan = l & 15;
    const int mBase = blockIdx.x * 64;
    const int nBase = blockIdx.y * 128;
    const int wm = (w & 1) * 32, wn = (w >> 1) * 64;
    const int bbU = mBase >> 11;
    const int ssBase = mBase & 2047;

    floatx4 acc[2][4];
    #pragma unroll
    for (int a = 0; a < 2; ++a)
        #pragma unroll
        for (int b = 0; b < 4; ++b)
            #pragma unroll
            for (int i = 0; i < 4; ++i) acc[a][b][i] = 0.f;

    const int sr = l >> 3;
    const int sgx = ((l & 7) ^ sr) * 8;

    for (int kt = 0; kt < 16; ++kt) {
        const int k0 = kt * 64;
        __syncthreads();
        #pragma unroll
        for (int i = 0; i < 2; ++i) {
            const int row = i * 32 + w * 8 + sr;
            gl_lds16(attn + ((size_t)(bbU * NH_ + kt) * SS_ + ssBase + row) * 64 + sgx,
                     As + i * 2048 + w * 512);
        }
        #pragma unroll
        for (int i = 0; i < 4; ++i) {
            const int row = i * 32 + w * 8 + sr;
            gl_lds16(WOt + (size_t)(nBase + row) * DD_ + k0 + sgx,
                     Bs + i * 2048 + w * 512);
        }
        __syncthreads();
        #pragma unroll
        for (int ks = 0; ks < 2; ++ks) {
            const int fo = (((ks * 4 + quad) ^ (lan & 7)) << 3);
            bf16x8 a[2], b[4];
            #pragma unroll
            for (int mi = 0; mi < 2; ++mi)
                a[mi] = *(const bf16x8*)(As + (wm + mi * 16 + lan) * 64 + fo);
            #pragma unroll
            for (int ni = 0; ni < 4; ++ni)
                b[ni] = *(const bf16x8*)(Bs + (wn + ni * 16 + lan) * 64 + fo);
            #pragma unroll
            for (int mi = 0; mi < 2; ++mi)
                #pragma unroll
                for (int ni = 0; ni < 4; ++ni)
                    acc[mi][ni] = __builtin_amdgcn_mfma_f32_16x16x32_bf16(
                        a[mi], b[ni], acc[mi][ni], 0, 0, 0);
        }
    }
    #pragma unroll
    for (int mi = 0; mi < 2; ++mi)
        #pragma unroll
        for (int ni = 0; ni < 4; ++ni)
            #pragma unroll
            for (int reg = 0; reg < 4; ++reg) {
                int m = mBase + wm + mi * 16 + quad * 4 + reg;
                out[(size_t)m * DD_ + nBase + wn + ni * 16 + lan] = acc[mi][ni][reg];
            }
}

extern "C" void kernel_launch(void* const* d_in, const int* in_sizes, int n_in,
                              void* d_out, int out_size, void* d_ws, size_t ws_size,
                              hipStream_t stream) {
    const float* resid = (const float*)d_in[0];
    const float* WQ    = (const float*)d_in[1];
    const float* WK    = (const float*)d_in[2];
    const float* WV    = (const float*)d_in[3];
    const float* WO    = (const float*)d_in[4];
    float* out = (float*)d_out;

    unsigned short* q      = (unsigned short*)d_ws;
    unsigned short* kk     = q      + 4194304;
    unsigned short* vT     = kk     + 4194304;
    unsigned short* attn   = vT     + 4194304;
    unsigned short* residB = attn   + 4194304;
    unsigned short* WQb    = residB + 4194304;
    unsigned short* WKb    = WQb    + 1048576;
    unsigned short* WVb    = WKb    + 1048576;
    unsigned short* WOt    = WVb    + 1048576;

    prep_kernel<<<dim3(7424), 256, 0, stream>>>(
        resid, WQ, WK, WV, WO, residB, WQb, WKb, WVb, WOt);
    qkv_fused_kernel<<<dim3(32, 16), 512, 0, stream>>>(
        residB, WQb, WKb, WVb, q, kk, vT);
    flash_mfma_kernel<<<dim3(1024), dim3(256), 0, stream>>>(q, kk, vT, attn);
    out_m97_kernel<<<dim3(64, 8), 256, 0, stream>>>(attn, WOt, out);
}